// Round 7
// baseline (250.144 us; speedup 1.0000x reference)
//
#include <hip/hip_runtime.h>
#include <hip/hip_bf16.h>
#include <math.h>

typedef __attribute__((ext_vector_type(8))) short bf16x8;
typedef __attribute__((ext_vector_type(8))) short short8;
typedef __attribute__((ext_vector_type(4))) float f32x4;

__device__ __forceinline__ short f2bf(float f) {
    unsigned u = __float_as_uint(f);
    u += 0x7fffu + ((u >> 16) & 1u);
    return (short)(u >> 16);
}
__device__ __forceinline__ float bf2f(short s) {
    return __uint_as_float(((unsigned)(unsigned short)s) << 16);
}

// ---------------- block reduction helpers (blockDim.x == 256) ----------------
__device__ __forceinline__ float bsum(float v, float* red) {
    int t = threadIdx.x;
    red[t] = v; __syncthreads();
    #pragma unroll
    for (int s = 128; s >= 1; s >>= 1) {
        if (t < s) red[t] += red[t + s];
        __syncthreads();
    }
    float r = red[0]; __syncthreads();
    return r;
}

__device__ __forceinline__ float bmax(float v, float* red) {
    int t = threadIdx.x;
    red[t] = v; __syncthreads();
    #pragma unroll
    for (int s = 128; s >= 1; s >>= 1) {
        if (t < s) red[t] = fmaxf(red[t], red[t + s]);
        __syncthreads();
    }
    float r = red[0]; __syncthreads();
    return r;
}

struct Batch8 {
    const void* A[8];
    const void* B[8];
    const float* bias[8];
    const float* add[8];
    void* C[8];
};

// ---------------- BIG 128x128 MFMA GEMM (projections) ----------------
template<typename TA, typename TB, int EPI>
__global__ __launch_bounds__(256) void gemm_big_k(Batch8 bp, int lda, int ldb, int ldc,
                                                  int K, float scale)
{
    __shared__ __align__(16) short As[128 * 40];
    __shared__ __align__(16) short Bs[128 * 40];
    const int t = threadIdx.x;
    const int lane = t & 63;
    const int w = t >> 6, wm = w >> 1, wn = w & 1;
    const int bm = blockIdx.y * 128, bn = blockIdx.x * 128;
    const int l15 = lane & 15, l4 = lane >> 4;
    const TA* __restrict__ A = (const TA*)bp.A[blockIdx.z];
    const TB* __restrict__ B = (const TB*)bp.B[blockIdx.z];

    f32x4 acc[4][4];
    #pragma unroll
    for (int i = 0; i < 4; ++i)
        #pragma unroll
        for (int j = 0; j < 4; ++j)
            #pragma unroll
            for (int r = 0; r < 4; ++r) acc[i][j][r] = 0.f;

    for (int k0 = 0; k0 < K; k0 += 32) {
        if constexpr (sizeof(TA) == 4) {
            #pragma unroll
            for (int p = 0; p < 4; ++p) {
                int row = (t >> 3) + p * 32;
                int c4 = (t & 7) * 4;
                const float4 v = *reinterpret_cast<const float4*>(
                    A + (size_t)(bm + row) * lda + k0 + c4);
                short4 s4 = make_short4(f2bf(v.x), f2bf(v.y), f2bf(v.z), f2bf(v.w));
                *reinterpret_cast<short4*>(&As[row * 40 + c4]) = s4;
            }
        } else {
            #pragma unroll
            for (int p = 0; p < 2; ++p) {
                int row = (t >> 2) + p * 64;
                int c8 = (t & 3) * 8;
                short8 v = *reinterpret_cast<const short8*>(
                    A + (size_t)(bm + row) * lda + k0 + c8);
                *reinterpret_cast<short8*>(&As[row * 40 + c8]) = v;
            }
        }
        if constexpr (sizeof(TB) == 4) {
            #pragma unroll
            for (int p = 0; p < 4; ++p) {
                int row = (t >> 3) + p * 32;
                int c4 = (t & 7) * 4;
                const float4 v = *reinterpret_cast<const float4*>(
                    B + (size_t)(bn + row) * ldb + k0 + c4);
                short4 s4 = make_short4(f2bf(v.x), f2bf(v.y), f2bf(v.z), f2bf(v.w));
                *reinterpret_cast<short4*>(&Bs[row * 40 + c4]) = s4;
            }
        } else {
            #pragma unroll
            for (int p = 0; p < 2; ++p) {
                int row = (t >> 2) + p * 64;
                int c8 = (t & 3) * 8;
                short8 v = *reinterpret_cast<const short8*>(
                    B + (size_t)(bn + row) * ldb + k0 + c8);
                *reinterpret_cast<short8*>(&Bs[row * 40 + c8]) = v;
            }
        }
        __syncthreads();

        const bf16x8* Ap = reinterpret_cast<const bf16x8*>(As);
        const bf16x8* Bp = reinterpret_cast<const bf16x8*>(Bs);
        bf16x8 af[4], bfr[4];
        #pragma unroll
        for (int mi = 0; mi < 4; ++mi)
            af[mi] = Ap[(wm * 64 + mi * 16 + l15) * 5 + l4];
        #pragma unroll
        for (int ni = 0; ni < 4; ++ni)
            bfr[ni] = Bp[(wn * 64 + ni * 16 + l15) * 5 + l4];
        #pragma unroll
        for (int mi = 0; mi < 4; ++mi)
            #pragma unroll
            for (int ni = 0; ni < 4; ++ni)
                acc[mi][ni] = __builtin_amdgcn_mfma_f32_16x16x32_bf16(
                    af[mi], bfr[ni], acc[mi][ni], 0, 0, 0);
        __syncthreads();
    }

    const float* bias = bp.bias[blockIdx.z];
    short* __restrict__ C = (short*)bp.C[blockIdx.z];
    #pragma unroll
    for (int mi = 0; mi < 4; ++mi) {
        #pragma unroll
        for (int ni = 0; ni < 4; ++ni) {
            int col = bn + wn * 64 + ni * 16 + l15;
            #pragma unroll
            for (int r = 0; r < 4; ++r) {
                int row = bm + wm * 64 + mi * 16 + l4 * 4 + r;
                float v = acc[mi][ni][r] * scale;
                if (EPI == 1) v += bias[col];
                C[(size_t)row * ldc + col] = f2bf(v);
            }
        }
    }
}

// ---------------- fused attention: scores + row-softmax + head-mean ---------
// One block = 32 query rows of one tag; 8 waves x 128 keys = full 1024-key row.
// qk: 8 x [1024][512] bf16 (q_t,q_n,q_tn,q_nt,k_t,k_n,k_tn,k_nt). a: 4 x [1024][1024] bf16.
__global__ __launch_bounds__(512) void attn_k(const short* __restrict__ qk,
                                              short* __restrict__ a)
{
    __shared__ __align__(16) short Qs[32 * 520];
    __shared__ __align__(16) short Ks[1024 * 40];
    __shared__ float smx[2][32][8];
    __shared__ float ssum[2][32][8];
    const int t = threadIdx.x;
    const int tag = blockIdx.y;
    const int r0 = blockIdx.x * 32;
    const int wv = t >> 6, lane = t & 63;
    const int l15 = lane & 15, l4 = lane >> 4;
    const int kw0 = wv * 128;
    const short* Qb = qk + (size_t)tag * 524288;
    const short* Kb = qk + (size_t)(4 + tag) * 524288;
    short* aout = a + ((size_t)tag << 20);

    // stage Q: 32 rows x 512 feats
    {
        int row = t >> 4, cb = (t & 15) * 8;
        #pragma unroll
        for (int p = 0; p < 4; ++p) {
            short8 v = *reinterpret_cast<const short8*>(
                Qb + (size_t)(r0 + row) * 512 + cb + p * 128);
            *reinterpret_cast<short8*>(&Qs[row * 520 + cb + p * 128]) = v;
        }
    }

    f32x4 acc[2][2][8];
    #pragma unroll
    for (int h = 0; h < 2; ++h)
        #pragma unroll
        for (int mi = 0; mi < 2; ++mi)
            #pragma unroll
            for (int nf = 0; nf < 8; ++nf)
                #pragma unroll
                for (int r = 0; r < 4; ++r) acc[h][mi][nf][r] = 0.f;

    #pragma unroll
    for (int h = 0; h < 2; ++h) {
        #pragma unroll
        for (int ks = 0; ks < 8; ++ks) {
            __syncthreads();              // prev reads done (covers Q stage on iter 0)
            const int f0 = h * 256 + ks * 32;
            {
                int rr = t >> 2, c8 = (t & 3) * 8;
                #pragma unroll
                for (int p = 0; p < 8; ++p) {
                    short8 v = *reinterpret_cast<const short8*>(
                        Kb + (size_t)(p * 128 + rr) * 512 + f0 + c8);
                    *reinterpret_cast<short8*>(&Ks[(p * 128 + rr) * 40 + c8]) = v;
                }
            }
            __syncthreads();
            bf16x8 af[2], bfr[8];
            #pragma unroll
            for (int mi = 0; mi < 2; ++mi)
                af[mi] = *reinterpret_cast<const bf16x8*>(
                    &Qs[(mi * 16 + l15) * 520 + f0 + l4 * 8]);
            #pragma unroll
            for (int nf = 0; nf < 8; ++nf)
                bfr[nf] = *reinterpret_cast<const bf16x8*>(
                    &Ks[(kw0 + nf * 16 + l15) * 40 + l4 * 8]);
            #pragma unroll
            for (int mi = 0; mi < 2; ++mi)
                #pragma unroll
                for (int nf = 0; nf < 8; ++nf)
                    acc[h][mi][nf] = __builtin_amdgcn_mfma_f32_16x16x32_bf16(
                        af[mi], bfr[nf], acc[h][mi][nf], 0, 0, 0);
        }
    }

    // ---- row max over this wave's 128 keys (raw scores) ----
    float pm[2][2][4];
    #pragma unroll
    for (int h = 0; h < 2; ++h)
        #pragma unroll
        for (int mi = 0; mi < 2; ++mi)
            #pragma unroll
            for (int r = 0; r < 4; ++r) {
                float m = acc[h][mi][0][r];
                #pragma unroll
                for (int nf = 1; nf < 8; ++nf) m = fmaxf(m, acc[h][mi][nf][r]);
                pm[h][mi][r] = m;
            }
    #pragma unroll
    for (int off = 1; off <= 8; off <<= 1)
        #pragma unroll
        for (int h = 0; h < 2; ++h)
            #pragma unroll
            for (int mi = 0; mi < 2; ++mi)
                #pragma unroll
                for (int r = 0; r < 4; ++r)
                    pm[h][mi][r] = fmaxf(pm[h][mi][r], __shfl_xor(pm[h][mi][r], off));
    if (l15 == 0) {
        #pragma unroll
        for (int h = 0; h < 2; ++h)
            #pragma unroll
            for (int mi = 0; mi < 2; ++mi)
                #pragma unroll
                for (int r = 0; r < 4; ++r)
                    smx[h][mi * 16 + l4 * 4 + r][wv] = pm[h][mi][r];
    }
    __syncthreads();
    float gm[2][2][4];
    #pragma unroll
    for (int h = 0; h < 2; ++h)
        #pragma unroll
        for (int mi = 0; mi < 2; ++mi)
            #pragma unroll
            for (int r = 0; r < 4; ++r) {
                float m = smx[h][mi * 16 + l4 * 4 + r][0];
                #pragma unroll
                for (int w8 = 1; w8 < 8; ++w8)
                    m = fmaxf(m, smx[h][mi * 16 + l4 * 4 + r][w8]);
                gm[h][mi][r] = m;
            }

    // ---- exp (scaled) in place + row sums ----
    float ps[2][2][4];
    #pragma unroll
    for (int h = 0; h < 2; ++h)
        #pragma unroll
        for (int mi = 0; mi < 2; ++mi)
            #pragma unroll
            for (int r = 0; r < 4; ++r) ps[h][mi][r] = 0.f;
    #pragma unroll
    for (int h = 0; h < 2; ++h)
        #pragma unroll
        for (int mi = 0; mi < 2; ++mi)
            #pragma unroll
            for (int nf = 0; nf < 8; ++nf)
                #pragma unroll
                for (int r = 0; r < 4; ++r) {
                    float e = __expf(0.0625f * (acc[h][mi][nf][r] - gm[h][mi][r]));
                    acc[h][mi][nf][r] = e;
                    ps[h][mi][r] += e;
                }
    #pragma unroll
    for (int off = 1; off <= 8; off <<= 1)
        #pragma unroll
        for (int h = 0; h < 2; ++h)
            #pragma unroll
            for (int mi = 0; mi < 2; ++mi)
                #pragma unroll
                for (int r = 0; r < 4; ++r)
                    ps[h][mi][r] += __shfl_xor(ps[h][mi][r], off);
    if (l15 == 0) {
        #pragma unroll
        for (int h = 0; h < 2; ++h)
            #pragma unroll
            for (int mi = 0; mi < 2; ++mi)
                #pragma unroll
                for (int r = 0; r < 4; ++r)
                    ssum[h][mi * 16 + l4 * 4 + r][wv] = ps[h][mi][r];
    }
    __syncthreads();
    float rs[2][2][4];
    #pragma unroll
    for (int h = 0; h < 2; ++h)
        #pragma unroll
        for (int mi = 0; mi < 2; ++mi)
            #pragma unroll
            for (int r = 0; r < 4; ++r) {
                float s = 0.f;
                #pragma unroll
                for (int w8 = 0; w8 < 8; ++w8)
                    s += ssum[h][mi * 16 + l4 * 4 + r][w8];
                rs[h][mi][r] = 0.5f / s;
            }

    // ---- write head-mean ----
    #pragma unroll
    for (int mi = 0; mi < 2; ++mi)
        #pragma unroll
        for (int nf = 0; nf < 8; ++nf)
            #pragma unroll
            for (int r = 0; r < 4; ++r) {
                int row = r0 + mi * 16 + l4 * 4 + r;
                int col = kw0 + nf * 16 + l15;
                float v = acc[0][mi][nf][r] * rs[0][mi][r]
                        + acc[1][mi][nf][r] * rs[1][mi][r];
                aout[(size_t)row * 1024 + col] = f2bf(v);
            }
}

// ---------------- 64x64 batched MFMA GEMM ----------------
// EPI: 0 none, 1 +bias, 2 +bias+relu, 3 out = add + elu(v)
// WS: A(m,k) *= wsc[k] during staging. SUMB: B-operand = B + add (TRB fp32 path).
template<typename TA, typename TB, typename TC, bool TRA, bool TRB, int EPI,
         bool WS = false, bool SUMB = false>
__global__ __launch_bounds__(256) void gemm_b_k(Batch8 bp, int lda, int ldb, int ldc,
                                                int K, float scale,
                                                const float* __restrict__ wsc = nullptr)
{
    __shared__ __align__(16) short As[64 * 40];
    __shared__ __align__(16) short Bs[64 * 40];
    const int t = threadIdx.x;
    const int lane = t & 63;
    const int w = t >> 6, wm = w >> 1, wn = w & 1;
    const int bm = blockIdx.y * 64, bn = blockIdx.x * 64;
    const int l15 = lane & 15, l4 = lane >> 4;
    const TA* __restrict__ A = (const TA*)bp.A[blockIdx.z];
    const TB* __restrict__ B = (const TB*)bp.B[blockIdx.z];

    f32x4 acc[2][2];
    #pragma unroll
    for (int i = 0; i < 2; ++i)
        #pragma unroll
        for (int j = 0; j < 2; ++j)
            #pragma unroll
            for (int r = 0; r < 4; ++r) acc[i][j][r] = 0.f;

    for (int k0 = 0; k0 < K; k0 += 32) {
        if constexpr (!TRA) {
            if constexpr (sizeof(TA) == 4) {
                #pragma unroll
                for (int p = 0; p < 2; ++p) {
                    int row = (t >> 3) + p * 32;
                    int c4 = (t & 7) * 4;
                    float4 v = *reinterpret_cast<const float4*>(
                        A + (size_t)(bm + row) * lda + k0 + c4);
                    if constexpr (WS) {
                        v.x *= wsc[k0 + c4 + 0]; v.y *= wsc[k0 + c4 + 1];
                        v.z *= wsc[k0 + c4 + 2]; v.w *= wsc[k0 + c4 + 3];
                    }
                    short4 s4 = make_short4(f2bf(v.x), f2bf(v.y), f2bf(v.z), f2bf(v.w));
                    *reinterpret_cast<short4*>(&As[row * 40 + c4]) = s4;
                }
            } else {
                int row = t >> 2, c8 = (t & 3) * 8;
                short8 v = *reinterpret_cast<const short8*>(
                    A + (size_t)(bm + row) * lda + k0 + c8);
                *reinterpret_cast<short8*>(&As[row * 40 + c8]) = v;
            }
        } else {
            #pragma unroll
            for (int p = 0; p < 2; ++p) {
                int kk = (t >> 4) + p * 16;
                int m4 = (t & 15) * 4;
                const float4 v = *reinterpret_cast<const float4*>(
                    (const float*)A + (size_t)(k0 + kk) * lda + bm + m4);
                As[(m4 + 0) * 40 + kk] = f2bf(v.x);
                As[(m4 + 1) * 40 + kk] = f2bf(v.y);
                As[(m4 + 2) * 40 + kk] = f2bf(v.z);
                As[(m4 + 3) * 40 + kk] = f2bf(v.w);
            }
        }
        if constexpr (!TRB) {
            if constexpr (sizeof(TB) == 4) {
                #pragma unroll
                for (int p = 0; p < 2; ++p) {
                    int row = (t >> 3) + p * 32;
                    int c4 = (t & 7) * 4;
                    const float4 v = *reinterpret_cast<const float4*>(
                        B + (size_t)(bn + row) * ldb + k0 + c4);
                    short4 s4 = make_short4(f2bf(v.x), f2bf(v.y), f2bf(v.z), f2bf(v.w));
                    *reinterpret_cast<short4*>(&Bs[row * 40 + c4]) = s4;
                }
            } else {
                int row = t >> 2, c8 = (t & 3) * 8;
                short8 v = *reinterpret_cast<const short8*>(
                    B + (size_t)(bn + row) * ldb + k0 + c8);
                *reinterpret_cast<short8*>(&Bs[row * 40 + c8]) = v;
            }
        } else {
            #pragma unroll
            for (int p = 0; p < 2; ++p) {
                int kk = (t >> 4) + p * 16;
                int n4 = (t & 15) * 4;
                float4 v = *reinterpret_cast<const float4*>(
                    (const float*)B + (size_t)(k0 + kk) * ldb + bn + n4);
                if constexpr (SUMB) {
                    const float4 v2 = *reinterpret_cast<const float4*>(
                        (const float*)bp.add[blockIdx.z] + (size_t)(k0 + kk) * ldb + bn + n4);
                    v.x += v2.x; v.y += v2.y; v.z += v2.z; v.w += v2.w;
                }
                Bs[(n4 + 0) * 40 + kk] = f2bf(v.x);
                Bs[(n4 + 1) * 40 + kk] = f2bf(v.y);
                Bs[(n4 + 2) * 40 + kk] = f2bf(v.z);
                Bs[(n4 + 3) * 40 + kk] = f2bf(v.w);
            }
        }
        __syncthreads();

        const bf16x8* Ap = reinterpret_cast<const bf16x8*>(As);
        const bf16x8* Bp = reinterpret_cast<const bf16x8*>(Bs);
        bf16x8 af[2], bfr[2];
        #pragma unroll
        for (int mi = 0; mi < 2; ++mi)
            af[mi] = Ap[(wm * 32 + mi * 16 + l15) * 5 + l4];
        #pragma unroll
        for (int ni = 0; ni < 2; ++ni)
            bfr[ni] = Bp[(wn * 32 + ni * 16 + l15) * 5 + l4];
        #pragma unroll
        for (int mi = 0; mi < 2; ++mi)
            #pragma unroll
            for (int ni = 0; ni < 2; ++ni)
                acc[mi][ni] = __builtin_amdgcn_mfma_f32_16x16x32_bf16(
                    af[mi], bfr[ni], acc[mi][ni], 0, 0, 0);
        __syncthreads();
    }

    const float* bias = bp.bias[blockIdx.z];
    const float* add = bp.add[blockIdx.z];
    TC* __restrict__ C = (TC*)bp.C[blockIdx.z];
    #pragma unroll
    for (int mi = 0; mi < 2; ++mi) {
        #pragma unroll
        for (int ni = 0; ni < 2; ++ni) {
            int col = bn + wn * 32 + ni * 16 + l15;
            #pragma unroll
            for (int r = 0; r < 4; ++r) {
                int row = bm + wm * 32 + mi * 16 + l4 * 4 + r;
                float v = acc[mi][ni][r] * scale;
                if (EPI == 1) v += bias[col];
                if (EPI == 2) v = fmaxf(v + bias[col], 0.f);
                if (EPI == 3) {
                    float e = v > 0.f ? v : (__expf(v) - 1.f);
                    v = add[(size_t)row * ldc + col] + e;
                }
                if constexpr (sizeof(TC) == 4) C[(size_t)row * ldc + col] = v;
                else C[(size_t)row * ldc + col] = f2bf(v);
            }
        }
    }
}

// ---------------- column standardize (ddof=1) + column softmax, batched ------
template<typename TOUT>
__global__ __launch_bounds__(256) void norm_softmax_b(const float* __restrict__ Zbase,
                                                      int zstride,
                                                      TOUT* __restrict__ Hout, int ldh,
                                                      int joffmul,
                                                      float* __restrict__ out2)
{
    __shared__ float red[256];
    const int j = blockIdx.x, t = threadIdx.x;
    const float* Z = Zbase + (size_t)blockIdx.y * zstride;
    const int joff = blockIdx.y * joffmul;

    float x[4];
    #pragma unroll
    for (int i = 0; i < 4; ++i) x[i] = Z[(size_t)(t + i * 256) * 256 + j];

    float s = x[0] + x[1] + x[2] + x[3];
    float mean = bsum(s, red) * (1.f / 1024.f);

    float ss = 0.f;
    #pragma unroll
    for (int i = 0; i < 4; ++i) { float d = x[i] - mean; ss += d * d; }
    float var = bsum(ss, red) * (1.f / 1023.f);
    float inv = 1.f / (sqrtf(var) + 1e-6f);

    float v[4];
    float mx = -3.4e38f;
    #pragma unroll
    for (int i = 0; i < 4; ++i) { v[i] = (x[i] - mean) * inv; mx = fmaxf(mx, v[i]); }
    mx = bmax(mx, red);

    float e[4], es = 0.f;
    #pragma unroll
    for (int i = 0; i < 4; ++i) { e[i] = __expf(v[i] - mx); es += e[i]; }
    es = bsum(es, red);
    float invs = 1.f / es;

    #pragma unroll
    for (int i = 0; i < 4; ++i) {
        float o = e[i] * invs;
        if constexpr (sizeof(TOUT) == 4)
            Hout[(size_t)(t + i * 256) * ldh + joff + j] = o;
        else
            Hout[(size_t)(t + i * 256) * ldh + joff + j] = f2bf(o);
        if (out2) out2[(size_t)(t + i * 256) * 256 + joff + j] = o;
    }
}

// ---------------- fusion split-K reduce: z1f = bf16(relu(sum_s + b)) ---------
__global__ __launch_bounds__(256) void freduce_k(const float* __restrict__ Cpartf,
                                                 const float* __restrict__ b,
                                                 short* __restrict__ z1f)
{
    int i = blockIdx.x * 256 + threadIdx.x;
    float s = b[i & 255];
    #pragma unroll
    for (int z = 0; z < 4; ++z) s += Cpartf[(size_t)z * 262144 + i];
    z1f[i] = f2bf(fmaxf(s, 0.f));
}

// ---------------- Cpart[s][j][k] = sum_{n in slab s(64)} H[n,j]*log(0.5*(H[n,j]+H[n,k]))
__global__ __launch_bounds__(256) void jsd_part_k(const float* __restrict__ H,
                                                  float* __restrict__ Cpart)
{
    __shared__ float hj[8][33];
    __shared__ float hk[8][33];
    const int t = threadIdx.x;
    const int tx = t & 15, ty = t >> 4;
    const int j0 = blockIdx.y * 32, k0 = blockIdx.x * 32;
    const int nbase = blockIdx.z * 64;

    float acc[2][2] = {};

    for (int c = 0; c < 8; ++c) {
        int n0 = nbase + c * 8;
        int nl = t >> 5, cc = t & 31;
        hj[nl][cc] = H[(size_t)(n0 + nl) * 256 + j0 + cc];
        hk[nl][cc] = H[(size_t)(n0 + nl) * 256 + k0 + cc];
        __syncthreads();
        #pragma unroll
        for (int nn = 0; nn < 8; ++nn) {
            float a0 = hj[nn][ty * 2], a1 = hj[nn][ty * 2 + 1];
            float b0 = hk[nn][tx * 2], b1 = hk[nn][tx * 2 + 1];
            acc[0][0] += a0 * __logf(0.5f * (a0 + b0));
            acc[0][1] += a0 * __logf(0.5f * (a0 + b1));
            acc[1][0] += a1 * __logf(0.5f * (a1 + b0));
            acc[1][1] += a1 * __logf(0.5f * (a1 + b1));
        }
        __syncthreads();
    }
    float* Cp = Cpart + (size_t)blockIdx.z * 65536;
    #pragma unroll
    for (int i = 0; i < 2; ++i)
        #pragma unroll
        for (int jj = 0; jj < 2; ++jj)
            Cp[(size_t)(j0 + ty * 2 + i) * 256 + k0 + tx * 2 + jj] = acc[i][jj];
}

// ---------------- per-k row/col sums over 16 slabs; ent[k] = diag(C) --------
__global__ __launch_bounds__(256) void rc_k(const float* __restrict__ Cpart,
                                            float* __restrict__ cmv,
                                            float* __restrict__ rmv,
                                            float* __restrict__ entv)
{
    __shared__ float red[256];
    const int k = blockIdx.x, j = threadIdx.x;
    float cm = 0.f, rm = 0.f;
    #pragma unroll
    for (int s = 0; s < 16; ++s) {
        cm += Cpart[(size_t)s * 65536 + (size_t)j * 256 + k];
        rm += Cpart[(size_t)s * 65536 + (size_t)k * 256 + j];
    }
    if (j == k) entv[k] = cm;
    cm = bsum(cm, red);
    rm = bsum(rm, red);
    if (j == 0) { cmv[k] = cm; rmv[k] = rm; }
}

// ---------------- jm -> standardize -> softmax -> w ----------------
__global__ __launch_bounds__(256) void jmw_k(const float* __restrict__ cmv,
                                             const float* __restrict__ rmv,
                                             const float* __restrict__ ent,
                                             float* __restrict__ w)
{
    __shared__ float red[256];
    const int k = threadIdx.x;
    float e = ent[k];
    float esum = bsum(e, red);

    float jm = 0.5f * (esum * (1.f / 256.f) + e - (cmv[k] + rmv[k]) * (1.f / 256.f));

    float mean = bsum(jm, red) * (1.f / 256.f);
    float d = jm - mean;
    float var = bsum(d * d, red) * (1.f / 255.f);
    float v = d / (sqrtf(var) + 1e-6f);

    float mx = bmax(v, red);
    float ex = __expf(v - mx);
    float s = bsum(ex, red);
    w[k] = ex / s;
}

// ---------------- launch ----------------
extern "C" void kernel_launch(void* const* d_in, const int* in_sizes, int n_in,
                              void* d_out, int out_size, void* d_ws, size_t ws_size,
                              hipStream_t stream) {
    const float* x_time = (const float*)d_in[0];
    const float* x_news = (const float*)d_in[1];
    const float* f1w = (const float*)d_in[34];
    const float* f1b = (const float*)d_in[35];
    const float* f2w = (const float*)d_in[36];
    const float* f2b = (const float*)d_in[37];
    const float* theta_t = (const float*)d_in[38];
    const float* theta_n = (const float*)d_in[39];
    float* out = (float*)d_out;

    float* ws = (float*)d_ws;
    // region 0 [0..2097152 fl): qk (8 x 524288 halves) -> Hcat (1024x1024 halves)
    short* s_qk = (short*)ws;
    short* s_Hc = (short*)ws;                    // aliases qk (dead after attn)
    // region 1 [2097152..4194304 fl): a (4 x 1M halves) -> later scratch
    short* s_a    = (short*)(ws + 2097152);      // 8 MB
    float* Cpartf = ws + 2097152;                // 4 x 262144 fl (a dead after MLP1)
    float* Cpart  = ws + 2097152;                // 16 x 65536 fl (jsd)
    float* entv   = ws + 3145728;
    float* cmv    = entv + 256;
    float* rmv    = cmv + 256;
    float* wv     = rmv + 256;
    float* Gpart  = ws + 3407872;                // 4 x 131072 fl
    // region 2 [4194304..5767168 fl): z1 (bf16) + z2 (fp32) -> Pbuf
    short* s_z1   = (short*)(ws + 4194304);      // 4 x 262144 halves
    float* z2b    = ws + 4718592;                // 4 x 262144 fl
    short* z1f    = s_z1;
    float* z2f    = z2b;
    float* Pbuf   = ws + 4194304;                // 2 x 524288 fl (z1/z2 dead by then)
    // persistent:
    float* Hbuf   = ws + 6291456;                // 262144 fl (peak 26.2 MB)

    const float* qsrc[4]  = {x_time, x_news, x_time, x_news};
    const float* kvsrc[4] = {x_time, x_news, x_news, x_time};
    const int    base[4]  = {2, 10, 18, 26};

    Batch8 bp{};

    // ======== projections: z=8 {q_t,q_n,q_tn,q_nt,k_t,k_n,k_tn,k_nt} ========
    for (int tg = 0; tg < 4; ++tg) {
        bp.A[tg] = qsrc[tg];      bp.B[tg] = d_in[base[tg] + 0];
        bp.bias[tg] = (const float*)d_in[base[tg] + 2];
        bp.C[tg] = s_qk + (size_t)tg * 524288;
        bp.A[4 + tg] = kvsrc[tg]; bp.B[4 + tg] = d_in[base[tg] + 1];
        bp.bias[4 + tg] = (const float*)d_in[base[tg] + 3];
        bp.C[4 + tg] = s_qk + (size_t)(4 + tg) * 524288;
    }
    gemm_big_k<float, float, 1>
        <<<dim3(4, 8, 8), 256, 0, stream>>>(bp, 512, 512, 512, 512, 1.f);

    // ======== fused attention: scores + softmax + head-mean -> a ========
    attn_k<<<dim3(32, 4), 512, 0, stream>>>(s_qk, s_a);

    // ======== incidence MLP1 (direct, z=4, K=1024, bias+relu) ========
    for (int tg = 0; tg < 4; ++tg) {
        bp.A[tg] = s_a + ((size_t)tg << 20);
        bp.B[tg] = d_in[base[tg] + 4];
        bp.bias[tg] = (const float*)d_in[base[tg] + 5];
        bp.C[tg] = s_z1 + (size_t)tg * 262144;
    }
    gemm_b_k<short, float, short, false, false, 2>
        <<<dim3(4, 16, 4), 256, 0, stream>>>(bp, 1024, 1024, 256, 1024, 1.f);

    // ======== incidence MLP2 z=4 ========
    for (int tg = 0; tg < 4; ++tg) {
        bp.A[tg] = s_z1 + (size_t)tg * 262144;
        bp.B[tg] = d_in[base[tg] + 6];
        bp.bias[tg] = (const float*)d_in[base[tg] + 7];
        bp.C[tg] = z2b + (size_t)tg * 262144;
    }
    gemm_b_k<short, float, float, false, false, 1>
        <<<dim3(4, 16, 4), 256, 0, stream>>>(bp, 256, 256, 256, 256, 1.f);

    // norm_softmax over 4 tags -> Hcat (bf16)
    norm_softmax_b<short><<<dim3(256, 4), 256, 0, stream>>>(z2b, 262144, s_Hc, 1024, 256, nullptr);

    // ======== fusion MLP (split-K z=4) + norm_softmax -> Hbuf (+out H) ========
    for (int z = 0; z < 4; ++z) {
        bp.A[z] = s_Hc + z * 256;
        bp.B[z] = f1w + z * 256;
        bp.bias[z] = nullptr;
        bp.C[z] = Cpartf + (size_t)z * 262144;
    }
    gemm_b_k<short, float, float, false, false, 0>
        <<<dim3(4, 16, 4), 256, 0, stream>>>(bp, 1024, 1024, 256, 256, 1.f);
    freduce_k<<<1024, 256, 0, stream>>>(Cpartf, f1b, z1f);

    bp.A[0] = z1f; bp.B[0] = f2w; bp.bias[0] = f2b; bp.C[0] = z2f;
    gemm_b_k<short, float, float, false, false, 1>
        <<<dim3(4, 16, 1), 256, 0, stream>>>(bp, 256, 256, 256, 256, 1.f);
    norm_softmax_b<float><<<dim3(256, 1), 256, 0, stream>>>(z2f, 0, Hbuf, 256, 0,
                                                            out + 1048576);

    // ======== JSD -> w ========
    jsd_part_k<<<dim3(8, 8, 16), 256, 0, stream>>>(Hbuf, Cpart);
    rc_k<<<256, 256, 0, stream>>>(Cpart, cmv, rmv, entv);
    jmw_k<<<1, 256, 0, stream>>>(cmv, rmv, entv, wv);

    // ======== finals: G = H^T X (split-K z=4), P = (H*w)(G0+G1), out = x+elu(P theta)
    const float* xc[2] = {x_time, x_news};
    const float* th[2] = {theta_t, theta_n};
    for (int i = 0; i < 4; ++i) {                 // i = chain*2 + slab
        int chain = i >> 1, slab = i & 1;
        bp.A[i] = Hbuf + (size_t)slab * 512 * 256;
        bp.B[i] = xc[chain] + (size_t)slab * 512 * 512;
        bp.bias[i] = nullptr;
        bp.C[i] = Gpart + (size_t)i * 131072;
    }
    gemm_b_k<float, float, float, true, true, 0>
        <<<dim3(8, 4, 4), 256, 0, stream>>>(bp, 256, 512, 512, 512, 1.f);

    for (int c = 0; c < 2; ++c) {
        bp.A[c] = Hbuf;                            // WS applies w[k]
        bp.B[c] = Gpart + (size_t)(c * 2 + 0) * 131072;
        bp.add[c] = Gpart + (size_t)(c * 2 + 1) * 131072;   // SUMB second half
        bp.bias[c] = nullptr;
        bp.C[c] = Pbuf + (size_t)c * 524288;
    }
    gemm_b_k<float, float, float, false, true, 0, true, true>
        <<<dim3(8, 16, 2), 256, 0, stream>>>(bp, 256, 512, 512, 256, 1.f, wv);

    for (int c = 0; c < 2; ++c) {
        bp.A[c] = Pbuf + (size_t)c * 524288;
        bp.B[c] = th[c];
        bp.bias[c] = nullptr;
        bp.add[c] = xc[c];
        bp.C[c] = out + (size_t)c * 524288;
    }
    gemm_b_k<float, float, float, false, true, 3>
        <<<dim3(8, 16, 2), 256, 0, stream>>>(bp, 512, 512, 512, 512, 1.f);
}